// Round 6
// baseline (426.581 us; speedup 1.0000x reference)
//
#include <hip/hip_runtime.h>
#include <math.h>

#define B_ 4
#define T_ 2048
#define DM_ 1024
#define H_ 16
#define D_ 64
#define BT_ 16
#define NC_ 128

typedef _Float16 half8 __attribute__((ext_vector_type(8)));
typedef _Float16 half4 __attribute__((ext_vector_type(4)));
typedef float f32x4 __attribute__((ext_vector_type(4)));

#define MFMA16 __builtin_amdgcn_mfma_f32_16x16x32_f16

// ---- async global->LDS: 16B per lane, wave-uniform LDS base + lane*16 ----
__device__ __forceinline__ void stage16(const _Float16* g, _Float16* l) {
  __builtin_amdgcn_global_load_lds(
      (const __attribute__((address_space(1))) unsigned int*)(const void*)g,
      (__attribute__((address_space(3))) unsigned int*)(void*)l, 16, 0, 0);
}

// ---- fast wave64 all-reduce sum: DPP prefix + row_bcast + readlane ----
template <int CTRL>
__device__ __forceinline__ float dppadd(float x) {
  return x + __int_as_float(__builtin_amdgcn_update_dpp(0, __float_as_int(x), CTRL, 0xf, 0xf, true));
}
__device__ __forceinline__ float wrs(float v) {
  v = dppadd<0x111>(v);
  v = dppadd<0x112>(v);
  v = dppadd<0x114>(v);
  v = dppadd<0x118>(v);
  v = dppadd<0x142>(v);
  v = dppadd<0x143>(v);
  return __int_as_float(__builtin_amdgcn_readlane(__float_as_int(v), 63));
}

// byte offset into a [rows][64] f16 tile: 128B rows, 16B slots XOR-swizzled
__device__ __forceinline__ int sw128(int row, int slot) {
  return row * 128 + ((slot ^ (row & 7)) * 16);
}
// byte offset into a [rows][32] f16 tile: 64B rows (halves 0-15 data, 16-31 zero),
// 16B slots XOR-swizzled by (row>>1)&3
__device__ __forceinline__ int p64(int row, int slot) {
  return row * 64 + ((slot ^ ((row >> 1) & 3)) * 16);
}

// ---------------- RoPE tables: cos/sin (T x 32) ----------------
__global__ void k_rope_table(float* __restrict__ cosT, float* __restrict__ sinT) {
  int idx = blockIdx.x * blockDim.x + threadIdx.x;
  if (idx >= T_ * 32) return;
  int t = idx >> 5, i = idx & 31;
  float inv = powf(10000.0f, -((float)(2 * i)) / 64.0f);
  float f = (float)t * inv;
  cosT[idx] = cosf(f);
  sinT[idx] = sinf(f);
}

// ---------------- eta = 0.01*sigmoid(x @ Wlr^T) ----------------
__global__ __launch_bounds__(256) void k_eta(const float* __restrict__ x,
                                             const float* __restrict__ Wlr,
                                             float* __restrict__ eta) {
  int w = threadIdx.x >> 6, l = threadIdx.x & 63;
  int row = blockIdx.x * 4 + w;
  const float* xr = x + (size_t)row * DM_;
  float s = 0.f;
#pragma unroll
  for (int j = 0; j < DM_ / 64; ++j) s += xr[j * 64 + l] * Wlr[j * 64 + l];
  s = wrs(s);
  if (l == 0) eta[row] = 0.01f / (1.0f + expf(-s));
}

// ---------------- fp32 -> fp16 conversion: x and Wq/Wk/Wv/Wo ----------------
__global__ __launch_bounds__(256) void k_cvt(const float* __restrict__ x,
                                             const float* __restrict__ Wq,
                                             const float* __restrict__ Wk,
                                             const float* __restrict__ Wv,
                                             const float* __restrict__ Wo,
                                             _Float16* __restrict__ xh,
                                             _Float16* __restrict__ wh) {
  int gid = blockIdx.x * 256 + threadIdx.x;
  const float* src;
  _Float16* dst;
  size_t off;
  if (gid < 1048576) {
    src = x; dst = xh; off = (size_t)gid * 8;
  } else {
    int j = gid - 1048576;
    int sel = j >> 17, jj = j & 131071;
    src = (sel == 0) ? Wq : (sel == 1) ? Wk : (sel == 2) ? Wv : Wo;
    dst = wh + (size_t)sel * 1048576;
    off = (size_t)jj * 8;
  }
  float4 a = *(const float4*)&src[off];
  float4 b = *(const float4*)&src[off + 4];
  half8 h;
  h[0] = (_Float16)a.x; h[1] = (_Float16)a.y; h[2] = (_Float16)a.z; h[3] = (_Float16)a.w;
  h[4] = (_Float16)b.x; h[5] = (_Float16)b.y; h[6] = (_Float16)b.z; h[7] = (_Float16)b.w;
  *(half8*)&dst[off] = h;
}

// ---------------- QKV GEMM (f16 MFMA, gload_lds staging) + fused RoPE, fp16 out ----------------
__global__ __launch_bounds__(256) void k_gemm_qkv_h(const _Float16* __restrict__ xh,
                                                    const _Float16* __restrict__ wh,
                                                    const float* __restrict__ cosT,
                                                    const float* __restrict__ sinT,
                                                    _Float16* __restrict__ qo,
                                                    _Float16* __restrict__ ko,
                                                    _Float16* __restrict__ vo) {
  __shared__ __align__(16) union {
    _Float16 ab[2][128 * 64];
    _Float16 ep[128][136];
  } sm;
  _Float16* As = sm.ab[0];
  _Float16* Bs = sm.ab[1];
  int tid = threadIdx.x;
  int m0 = blockIdx.x * 128;
  int by = blockIdx.y;
  int mat = by >> 3;
  int n0 = (by & 7) * 128;
  const _Float16* Bsrc = wh + (size_t)mat * 1048576;
  _Float16* op = (mat == 0) ? qo : (mat == 1) ? ko : vo;
  int wid = tid >> 6, l = tid & 63;
  int m0w = (wid >> 1) * 64, n0w = (wid & 1) * 64;
  int l15 = l & 15, l4 = l >> 4;

  f32x4 acc[4][4];
#pragma unroll
  for (int i = 0; i < 4; ++i)
#pragma unroll
    for (int j = 0; j < 4; ++j) acc[i][j] = (f32x4){0.f, 0.f, 0.f, 0.f};

  int srow_in = l >> 3;
  int schunk_l = l & 7;
  for (int k0 = 0; k0 < 1024; k0 += 64) {
#pragma unroll
    for (int i = 0; i < 4; ++i) {
      int row = wid * 32 + i * 8 + srow_in;
      int sc = schunk_l ^ (row & 7);
      stage16(xh + (size_t)(m0 + row) * 1024 + k0 + sc * 8, As + (wid * 32 + i * 8) * 64);
      stage16(Bsrc + (size_t)(n0 + row) * 1024 + k0 + sc * 8, Bs + (wid * 32 + i * 8) * 64);
    }
    __syncthreads();
#pragma unroll
    for (int kk = 0; kk < 2; ++kk) {
      half8 a[4], b[4];
#pragma unroll
      for (int mi = 0; mi < 4; ++mi) {
        int row = m0w + mi * 16 + l15;
        a[mi] = *(half8*)((char*)As + sw128(row, kk * 4 + l4));
      }
#pragma unroll
      for (int ni = 0; ni < 4; ++ni) {
        int row = n0w + ni * 16 + l15;
        b[ni] = *(half8*)((char*)Bs + sw128(row, kk * 4 + l4));
      }
#pragma unroll
      for (int mi = 0; mi < 4; ++mi)
#pragma unroll
        for (int ni = 0; ni < 4; ++ni)
          acc[mi][ni] = MFMA16(a[mi], b[ni], acc[mi][ni], 0, 0, 0);
    }
    __syncthreads();
  }

  if (mat < 2) {
#pragma unroll
    for (int mi = 0; mi < 4; ++mi)
#pragma unroll
      for (int r = 0; r < 4; ++r) {
        int m = m0 + m0w + mi * 16 + l4 * 4 + r;
        int t = m & (T_ - 1);
#pragma unroll
        for (int ni = 0; ni < 2; ++ni) {
          int d1 = ni * 16 + l15;
          float cv = cosT[t * 32 + d1];
          float sv = sinT[t * 32 + d1];
          float x1 = acc[mi][ni][r], x2 = acc[mi][ni + 2][r];
          acc[mi][ni][r] = x1 * cv - x2 * sv;
          acc[mi][ni + 2][r] = x2 * cv + x1 * sv;
        }
      }
  }

#pragma unroll
  for (int mi = 0; mi < 4; ++mi)
#pragma unroll
    for (int ni = 0; ni < 4; ++ni)
#pragma unroll
      for (int r = 0; r < 4; ++r) {
        int mrow = m0w + mi * 16 + l4 * 4 + r;
        int ncol = n0w + ni * 16 + l15;
        sm.ep[mrow][ncol] = (_Float16)acc[mi][ni][r];
      }
  __syncthreads();
  int bb = m0 >> 11, t0 = m0 & (T_ - 1);
#pragma unroll
  for (int seg = 0; seg < 2; ++seg) {
    int h0 = (by & 7) * 2 + seg;
    _Float16* dsth = op + ((size_t)(bb * H_ + h0) * T_ + t0) * D_;
#pragma unroll
    for (int p = 0; p < 4; ++p) {
      int idx = p * 256 + tid;
      int mrow = idx >> 3, c = idx & 7;
      half8 hv = *(half8*)&sm.ep[mrow][seg * 64 + c * 8];
      *(half8*)&dsth[mrow * 64 + c * 8] = hv;
    }
  }
}

// ---------------- out = zh @ Wo^T (fp32 out, coalesced epilogue) ----------------
__global__ __launch_bounds__(256) void k_gemm_out_h(const _Float16* __restrict__ zh,
                                                    const _Float16* __restrict__ woh,
                                                    float* __restrict__ out) {
  __shared__ __align__(16) union {
    _Float16 ab[2][128 * 64];
    float epf[64][132];
  } sm;
  _Float16* As = sm.ab[0];
  _Float16* Bs = sm.ab[1];
  int tid = threadIdx.x;
  int m0 = blockIdx.x * 128;
  int n0 = blockIdx.y * 128;
  int wid = tid >> 6, l = tid & 63;
  int m0w = (wid >> 1) * 64, n0w = (wid & 1) * 64;
  int l15 = l & 15, l4 = l >> 4;

  f32x4 acc[4][4];
#pragma unroll
  for (int i = 0; i < 4; ++i)
#pragma unroll
    for (int j = 0; j < 4; ++j) acc[i][j] = (f32x4){0.f, 0.f, 0.f, 0.f};

  int srow_in = l >> 3;
  int schunk_l = l & 7;
  for (int k0 = 0; k0 < 1024; k0 += 64) {
#pragma unroll
    for (int i = 0; i < 4; ++i) {
      int row = wid * 32 + i * 8 + srow_in;
      int sc = schunk_l ^ (row & 7);
      stage16(zh + (size_t)(m0 + row) * 1024 + k0 + sc * 8, As + (wid * 32 + i * 8) * 64);
      stage16(woh + (size_t)(n0 + row) * 1024 + k0 + sc * 8, Bs + (wid * 32 + i * 8) * 64);
    }
    __syncthreads();
#pragma unroll
    for (int kk = 0; kk < 2; ++kk) {
      half8 a[4], b[4];
#pragma unroll
      for (int mi = 0; mi < 4; ++mi) {
        int row = m0w + mi * 16 + l15;
        a[mi] = *(half8*)((char*)As + sw128(row, kk * 4 + l4));
      }
#pragma unroll
      for (int ni = 0; ni < 4; ++ni) {
        int row = n0w + ni * 16 + l15;
        b[ni] = *(half8*)((char*)Bs + sw128(row, kk * 4 + l4));
      }
#pragma unroll
      for (int mi = 0; mi < 4; ++mi)
#pragma unroll
        for (int ni = 0; ni < 4; ++ni)
          acc[mi][ni] = MFMA16(a[mi], b[ni], acc[mi][ni], 0, 0, 0);
    }
    __syncthreads();
  }

#pragma unroll
  for (int hi = 0; hi < 2; ++hi) {
    if ((wid >> 1) == hi) {
#pragma unroll
      for (int mi = 0; mi < 4; ++mi)
#pragma unroll
        for (int ni = 0; ni < 4; ++ni)
#pragma unroll
          for (int r = 0; r < 4; ++r)
            sm.epf[mi * 16 + l4 * 4 + r][n0w + ni * 16 + l15] = acc[mi][ni][r];
    }
    __syncthreads();
#pragma unroll
    for (int p = 0; p < 8; ++p) {
      int idx = p * 256 + tid;
      int mrow = idx >> 5, c = idx & 31;
      float4 v = *(float4*)&sm.epf[mrow][c * 4];
      *(float4*)&out[(size_t)(m0 + hi * 64 + mrow) * DM_ + n0 + c * 4] = v;
    }
    __syncthreads();
  }
}

// ---------------- TTT scan: wave-specialized pipeline, 1 block/(b,h), 8 waves ----------------
// Waves 0-3: W-chain (tK MFMA -> LN->ue -> W-update MFMA; W in f32 accs, e-rows w*16..).
// Waves 4-7: z-chain lagged 1 step (corr_{c-1} -> TQ-LN -> z) + qd_c/S_c MFMA + staging.
// 3 barriers per step.
__global__ __launch_bounds__(512) void k_scan(const _Float16* __restrict__ qg,
                                              const _Float16* __restrict__ kg,
                                              const _Float16* __restrict__ vg,
                                              const float* __restrict__ etag,
                                              const float* __restrict__ W0,
                                              const float* __restrict__ lnw_g,
                                              const float* __restrict__ lnb_g,
                                              _Float16* __restrict__ zg,
                                              float* __restrict__ wf) {
  __shared__ __align__(16) _Float16 Wh[4096];          // [e][d] 128B rows, sw128
  __shared__ __align__(16) _Float16 Kh[2][1024];       // [t][d] 128B rows, sw128 (via presw gload)
  __shared__ __align__(16) _Float16 Qh[2][1024];
  __shared__ __align__(16) _Float16 KTl[2][2048];      // [d][t] 64B rows p64, = -K, zero-pad
  __shared__ __align__(16) _Float16 UeTl[2][2048];     // [e][t] 64B rows p64, zero-pad
  __shared__ __align__(16) _Float16 Ssl[2][512];       // [t][s] 64B rows p64, = -S*mask, zero-pad
  __shared__ float tKs[16][68];
  __shared__ float tqs[16][68];

  int bh = blockIdx.x, b = bh >> 4, h = bh & 15;
  int tid = threadIdx.x, w = tid >> 6, l = tid & 63;
  int l15 = l & 15, g = l >> 4, u = w - 4;

  float lw = lnw_g[h * 64 + l];
  float lb = lnb_g[h * 64 + l];
  const _Float16* kb = kg + (size_t)bh * (T_ * D_);
  const _Float16* qb = qg + (size_t)bh * (T_ * D_);
  const _Float16* vb = vg + (size_t)bh * (T_ * D_);

  f32x4 accW[4];
  f32x4 accQ = (f32x4){0.f, 0.f, 0.f, 0.f};

  if (w < 4) {  // W0 -> accumulators + initial Wh
    const float* w0p = W0 + (size_t)bh * 4096;
#pragma unroll
    for (int dt = 0; dt < 4; ++dt)
#pragma unroll
      for (int r = 0; r < 4; ++r)
        accW[dt][r] = w0p[(w * 16 + g * 4 + r) * 64 + dt * 16 + l15];
#pragma unroll
    for (int dt = 0; dt < 4; ++dt)
#pragma unroll
      for (int r = 0; r < 4; ++r) {
        int e = w * 16 + g * 4 + r, d = dt * 16 + l15;
        *(_Float16*)((char*)Wh + e * 128 + (((d >> 3) ^ (e & 7)) * 16) + (d & 7) * 2) =
            (_Float16)accW[dt][r];
      }
  }
  // zero-init padded arrays (both bufs, all slots)
  for (int i = tid; i < 4096; i += 512) {
    ((_Float16*)KTl)[i] = (_Float16)0.f;
    ((_Float16*)UeTl)[i] = (_Float16)0.f;
  }
  for (int i = tid; i < 1024; i += 512) ((_Float16*)Ssl)[i] = (_Float16)0.f;
  __syncthreads();

  // stage chunk 0 into buf 0
  if (w >= 4) {
    const _Float16* src = (w < 6) ? kb : qb;
    _Float16* dst = (w < 6) ? Kh[0] : Qh[0];
    int hf = w & 1, row = hf * 8 + (l >> 3), ch = (l & 7) ^ (row & 7);
    stage16(src + row * 64 + ch * 8, dst + hf * 512);
    if (w == 4) {
      half8 ka = *(const half8*)(kb + (l & 15) * 64 + (l >> 4) * 16);
      half8 ka2 = *(const half8*)(kb + (l & 15) * 64 + (l >> 4) * 16 + 8);
#pragma unroll
      for (int i = 0; i < 16; ++i) {
        float v = (float)((i < 8) ? ka[i] : ka2[i - 8]);
        int d = (l >> 4) * 16 + i, t = l & 15;
        *(_Float16*)((char*)KTl[0] + d * 64 + ((((t >> 3)) ^ ((d >> 1) & 3)) * 16) + (t & 7) * 2) =
            (_Float16)(-v);
      }
    }
  }

  float kf[4], vf[4], et[4], qf[4];
#pragma unroll
  for (int i = 0; i < 4; ++i) { kf[i] = vf[i] = et[i] = qf[i] = 0.f; }

  for (int c = 0; c < NC_; ++c) {
    int cb = c & 1, p = cb ^ 1;
    __syncthreads();  // B1: staged buf[cb], Wh = W_c visible

    // ---- P1 ----
    if (w < 4) {
#pragma unroll
      for (int i = 0; i < 4; ++i) {  // prefetch K/V/eta for LN (L2-hot)
        int t = i * 4 + w;
        kf[i] = (float)kb[c * 1024 + t * 64 + l];
        vf[i] = (float)vb[c * 1024 + t * 64 + l];
        et[i] = etag[b * T_ + c * BT_ + t];
      }
      half8 bw0 = *(half8*)((char*)Wh + sw128(w * 16 + l15, g));
      half8 bw1 = *(half8*)((char*)Wh + sw128(w * 16 + l15, 4 + g));
      half8 ak0 = *(half8*)((char*)Kh[cb] + sw128(l15, g));
      half8 ak1 = *(half8*)((char*)Kh[cb] + sw128(l15, 4 + g));
      f32x4 a = (f32x4){0.f, 0.f, 0.f, 0.f};
      a = MFMA16(ak0, bw0, a, 0, 0, 0);
      a = MFMA16(ak1, bw1, a, 0, 0, 0);
#pragma unroll
      for (int r = 0; r < 4; ++r) tKs[g * 4 + r][w * 16 + l15] = a[r];
    } else {
      if (c > 0) {
#pragma unroll
        for (int i = 0; i < 4; ++i) {  // prefetch Q_{c-1} for z
          int t = i * 4 + u;
          qf[i] = (float)qb[(c - 1) * 1024 + t * 64 + l];
        }
        half8 as = *(half8*)((char*)Ssl[p] + p64(l15, g));
        half8 bu = *(half8*)((char*)UeTl[p] + p64(u * 16 + l15, g));
        accQ = MFMA16(as, bu, accQ, 0, 0, 0);  // TQ = qd - corr (signs folded)
#pragma unroll
        for (int r = 0; r < 4; ++r) tqs[g * 4 + r][u * 16 + l15] = accQ[r];
      }
    }
    half8 kpa = {0,0,0,0,0,0,0,0}, kpb = {0,0,0,0,0,0,0,0};
    if (w == 4 && c + 1 < NC_) {  // prefetch K_{c+1} for KT build
      kpa = *(const half8*)(kb + (size_t)(c + 1) * 1024 + (l & 15) * 64 + (l >> 4) * 16);
      kpb = *(const half8*)(kb + (size_t)(c + 1) * 1024 + (l & 15) * 64 + (l >> 4) * 16 + 8);
    }
    __syncthreads();  // B2: tKs, tqs visible

    // ---- P2 ----
    if (w < 4) {  // LN fwd+bwd -> ue -> UeT[cb]
#pragma unroll
      for (int i = 0; i < 4; ++i) {
        int t = i * 4 + w;
        float tkv = tKs[t][l];
        float s1 = wrs(tkv);
        float s2 = wrs(tkv * tkv);
        float mu = s1 * 0.015625f;
        float var = s2 * 0.015625f - mu * mu;
        float inv = rsqrtf(var + 1e-5f);
        float xhat = (tkv - mu) * inv;
        float ln = xhat * lw + lb;
        float gg = 0.125f * (kf[i] + ln - vf[i]);
        float dxh = gg * lw;
        float m1 = wrs(dxh) * 0.015625f;
        float m2 = wrs(dxh * xhat) * 0.015625f;
        float ue = (dxh - m1 - xhat * m2) * inv * et[i];
        *(_Float16*)((char*)UeTl[cb] + p64(l, t >> 3) + (t & 7) * 2) = (_Float16)ue;
      }
    } else {
      if (c > 0) {  // finish z_{c-1}
#pragma unroll
        for (int i = 0; i < 4; ++i) {
          int t = i * 4 + u;
          float tq = tqs[t][l];
          float s1 = wrs(tq);
          float s2 = wrs(tq * tq);
          float mu = s1 * 0.015625f;
          float var = s2 * 0.015625f - mu * mu;
          float inv = rsqrtf(var + 1e-5f);
          float zv = qf[i] + ((tq - mu) * inv) * lw + lb;
          zg[((size_t)(b * T_ + (c - 1) * BT_ + t)) * DM_ + h * 64 + l] = (_Float16)zv;
        }
      }
      // qd_c (and S_c on wave 4); Wh = W_c still stable until B3
      half8 bw0 = *(half8*)((char*)Wh + sw128(u * 16 + l15, g));
      half8 bw1 = *(half8*)((char*)Wh + sw128(u * 16 + l15, 4 + g));
      half8 aq0 = *(half8*)((char*)Qh[cb] + sw128(l15, g));
      half8 aq1 = *(half8*)((char*)Qh[cb] + sw128(l15, 4 + g));
      accQ = (f32x4){0.f, 0.f, 0.f, 0.f};
      accQ = MFMA16(aq0, bw0, accQ, 0, 0, 0);
      accQ = MFMA16(aq1, bw1, accQ, 0, 0, 0);
      if (w == 4) {
        half8 bk0 = *(half8*)((char*)Kh[cb] + sw128(l15, g));
        half8 bk1 = *(half8*)((char*)Kh[cb] + sw128(l15, 4 + g));
        f32x4 aS = (f32x4){0.f, 0.f, 0.f, 0.f};
        aS = MFMA16(aq0, bk0, aS, 0, 0, 0);
        aS = MFMA16(aq1, bk1, aS, 0, 0, 0);
#pragma unroll
        for (int r = 0; r < 4; ++r) {
          int t = g * 4 + r;
          _Float16 sv = (l15 < t) ? (_Float16)(-aS[r]) : (_Float16)0.f;
          *(_Float16*)((char*)Ssl[cb] + p64(t, l15 >> 3) + (l15 & 7) * 2) = sv;
        }
      }
    }
    __syncthreads();  // B3: UeT[cb], Ss[cb] visible; Wh reads done

    // ---- P3 ----
    if (w < 4) {  // W-update + Wh refresh
      half8 aU = *(half8*)((char*)UeTl[cb] + p64(w * 16 + l15, g));
#pragma unroll
      for (int dt = 0; dt < 4; ++dt) {
        half8 bK = *(half8*)((char*)KTl[cb] + p64(dt * 16 + l15, g));
        accW[dt] = MFMA16(aU, bK, accW[dt], 0, 0, 0);  // += ue^T @ (-K)
      }
#pragma unroll
      for (int dt = 0; dt < 4; ++dt)
#pragma unroll
        for (int r = 0; r < 4; ++r) {
          int e = w * 16 + g * 4 + r, d = dt * 16 + l15;
          *(_Float16*)((char*)Wh + e * 128 + (((d >> 3) ^ (e & 7)) * 16) + (d & 7) * 2) =
              (_Float16)accW[dt][r];
        }
    } else if (c + 1 < NC_) {  // stage chunk c+1 into buf cb^1
      int nb = cb ^ 1;
      const _Float16* src = (w < 6) ? kb : qb;
      _Float16* dst = (w < 6) ? Kh[nb] : Qh[nb];
      int hf = w & 1, row = hf * 8 + (l >> 3), ch = (l & 7) ^ (row & 7);
      stage16(src + (size_t)(c + 1) * 1024 + row * 64 + ch * 8, dst + hf * 512);
      if (w == 4) {
#pragma unroll
        for (int i = 0; i < 16; ++i) {
          float v = (float)((i < 8) ? kpa[i] : kpb[i - 8]);
          int d = (l >> 4) * 16 + i, t = l & 15;
          *(_Float16*)((char*)KTl[nb] + d * 64 + ((((t >> 3)) ^ ((d >> 1) & 3)) * 16) +
                       (t & 7) * 2) = (_Float16)(-v);
        }
      }
    }
  }

  // ---- drain: z for chunk NC-1 ; final W dump ----
  __syncthreads();
  {
    int p = (NC_ - 1) & 1;
    if (w >= 4) {
#pragma unroll
      for (int i = 0; i < 4; ++i) {
        int t = i * 4 + u;
        qf[i] = (float)qb[(size_t)(NC_ - 1) * 1024 + t * 64 + l];
      }
      half8 as = *(half8*)((char*)Ssl[p] + p64(l15, g));
      half8 bu = *(half8*)((char*)UeTl[p] + p64(u * 16 + l15, g));
      accQ = MFMA16(as, bu, accQ, 0, 0, 0);
#pragma unroll
      for (int r = 0; r < 4; ++r) tqs[g * 4 + r][u * 16 + l15] = accQ[r];
    }
  }
  __syncthreads();
  if (w >= 4) {
#pragma unroll
    for (int i = 0; i < 4; ++i) {
      int t = i * 4 + u;
      float tq = tqs[t][l];
      float s1 = wrs(tq);
      float s2 = wrs(tq * tq);
      float mu = s1 * 0.015625f;
      float var = s2 * 0.015625f - mu * mu;
      float inv = rsqrtf(var + 1e-5f);
      float zv = qf[i] + ((tq - mu) * inv) * lw + lb;
      zg[((size_t)(b * T_ + (NC_ - 1) * BT_ + t)) * DM_ + h * 64 + l] = (_Float16)zv;
    }
  } else {
#pragma unroll
    for (int dt = 0; dt < 4; ++dt)
#pragma unroll
      for (int r = 0; r < 4; ++r)
        wf[(size_t)bh * 4096 + (w * 16 + g * 4 + r) * 64 + dt * 16 + l15] = accW[dt][r];
  }
}

extern "C" void kernel_launch(void* const* d_in, const int* in_sizes, int n_in,
                              void* d_out, int out_size, void* d_ws, size_t ws_size,
                              hipStream_t stream) {
  const float* x   = (const float*)d_in[0];
  const float* W0  = (const float*)d_in[1];
  const float* Wq  = (const float*)d_in[2];
  const float* Wk  = (const float*)d_in[3];
  const float* Wv  = (const float*)d_in[4];
  const float* Wo  = (const float*)d_in[5];
  const float* Wlr = (const float*)d_in[6];
  const float* lnw = (const float*)d_in[7];
  const float* lnb = (const float*)d_in[8];
  float* out = (float*)d_out;
  float* ws = (float*)d_ws;

  float* eta  = ws;                          // 8192 f
  float* cosT = eta + 8192;                  // 65536 f
  float* sinT = cosT + 65536;                // 65536 f
  _Float16* q  = (_Float16*)(sinT + 65536);  // 8,388,608 halves (B,H,T,D)
  _Float16* k  = q + 8388608;
  _Float16* v  = k + 8388608;
  _Float16* xh = v + 8388608;                // 8,388,608 halves
  _Float16* wh = xh + 8388608;               // 4x 1,048,576 halves
  _Float16* zh = xh;                         // alias: xh dead after qkv GEMM
  float* wf = out + 8388608;                 // output #2: final W

  hipLaunchKernelGGL(k_rope_table, dim3(256), dim3(256), 0, stream, cosT, sinT);
  hipLaunchKernelGGL(k_cvt, dim3(6144), dim3(256), 0, stream, x, Wq, Wk, Wv, Wo, xh, wh);
  hipLaunchKernelGGL(k_eta, dim3(2048), dim3(256), 0, stream, x, Wlr, eta);
  hipLaunchKernelGGL(k_gemm_qkv_h, dim3(64, 24), dim3(256), 0, stream, xh, wh, cosT, sinT, q, k, v);
  hipLaunchKernelGGL(k_scan, dim3(64), dim3(512), 0, stream, q, k, v, eta, W0, lnw, lnb, zh, wf);
  hipLaunchKernelGGL(k_gemm_out_h, dim3(64, 8), dim3(256), 0, stream, zh, wh + 3145728, out);
}